// Round 12
// baseline (1156.654 us; speedup 1.0000x reference)
//
#include <hip/hip_runtime.h>
#include <math.h>

#define Bb 64
#define Tt 512
#define Dd 256
#define Nn 1024
#define NROWS 32768

// d_out layout (floats)
#define OUT_SOM 0L
#define OUT_SCAL 8388608L
#define OUT_Q 8388613L
#define OUT_BMU 41943045L

typedef __attribute__((ext_vector_type(8))) short bf16x8;
typedef __attribute__((ext_vector_type(4))) float f32x4;
typedef unsigned long long u64;
typedef unsigned short ushortT;

static __device__ __forceinline__ unsigned short f2bf(float x) {
  unsigned int u = __float_as_uint(x);
  unsigned int r = (u + 0x7fffu + ((u >> 16) & 1u)) >> 16;
  return (unsigned short)r;
}
static __device__ __forceinline__ float bf2f(unsigned short b) {
  return __uint_as_float(((unsigned int)b) << 16);
}

static __device__ __forceinline__ float block_reduce_sum(float v, float* sb) {
#pragma unroll
  for (int o = 32; o > 0; o >>= 1) v += __shfl_down(v, o, 64);
  const int lane = threadIdx.x & 63, w = threadIdx.x >> 6;
  if (lane == 0) sb[w] = v;
  __syncthreads();
  return (threadIdx.x == 0) ? (sb[0] + sb[1] + sb[2] + sb[3]) : 0.0f;
}

// ============ k_conv3: A2 row-major [zh|zl] + node FRAGMENT layout ============
__global__ __launch_bounds__(256) void k_conv3(
    const float* __restrict__ z, const float* __restrict__ nodes,
    ushortT* __restrict__ A2, ushortT* __restrict__ nhiF, ushortT* __restrict__ nloF,
    float* __restrict__ zn, float* __restrict__ nnorm) {
  __shared__ float sm[32 * 260];
  const int tid = threadIdx.x;
  if (blockIdx.x < 8192) {
    const int lane = tid & 63, w = tid >> 6;
    const long row = (long)blockIdx.x * 4 + w;
    const int t = (int)(row & (Tt - 1));
    const float tw = powf(0.9f, (float)(Tt - 1 - t));
    const float4 v = ((const float4*)(z + row * Dd))[lane];
    float x0 = v.x * tw, x1 = v.y * tw, x2 = v.z * tw, x3 = v.w * tw;
    ushort4 h, l;
    h.x = f2bf(x0); l.x = f2bf(x0 - bf2f(h.x));
    h.y = f2bf(x1); l.y = f2bf(x1 - bf2f(h.y));
    h.z = f2bf(x2); l.z = f2bf(x2 - bf2f(h.z));
    h.w = f2bf(x3); l.w = f2bf(x3 - bf2f(h.w));
    *(ushort4*)(A2 + row * 512 + lane * 4) = h;
    *(ushort4*)(A2 + row * 512 + 256 + lane * 4) = l;
    float s = x0 * x0 + x1 * x1 + x2 * x2 + x3 * x3;
#pragma unroll
    for (int o = 32; o > 0; o >>= 1) s += __shfl_down(s, o, 64);
    if (lane == 0) zn[row] = s;
  } else {
    const int ct = blockIdx.x - 8192;  // 0..63
    const int jr = tid >> 4, cg = tid & 15;
    const long nrow = (long)(ct * 16 + jr);
    float nrm = 0.f;
#pragma unroll
    for (int k = 0; k < 4; ++k) {
      const int c4 = cg + k * 16;
      const float4 v = ((const float4*)(nodes + nrow * Dd))[c4];
      *(float4*)&sm[jr * 260 + c4 * 4] = v;
      nrm += v.x * v.x + v.y * v.y + v.z * v.z + v.w * v.w;
    }
    nrm += __shfl_xor(nrm, 1, 64);
    nrm += __shfl_xor(nrm, 2, 64);
    nrm += __shfl_xor(nrm, 4, 64);
    nrm += __shfl_xor(nrm, 8, 64);
    if (cg == 0) nnorm[nrow] = nrm;
    __syncthreads();
    ushort4* oh = (ushort4*)(nhiF + (long)ct * 4096);
    ushort4* ol = (ushort4*)(nloF + (long)ct * 4096);
#pragma unroll
    for (int i = 0; i < 4; ++i) {
      const int o4 = tid + 256 * i;
      const int e4 = (o4 & 1) * 4;
      const int c16 = (o4 >> 1) & 15;
      const int k8 = (o4 >> 5) & 3;
      const int ks = o4 >> 7;
      const float* p = &sm[c16 * 260 + ks * 32 + k8 * 8 + e4];
      const float4 v = *(const float4*)p;
      ushort4 h, l;
      h.x = f2bf(v.x); l.x = f2bf(v.x - bf2f(h.x));
      h.y = f2bf(v.y); l.y = f2bf(v.y - bf2f(h.y));
      h.z = f2bf(v.z); l.z = f2bf(v.z - bf2f(h.z));
      h.w = f2bf(v.w); l.w = f2bf(v.w - bf2f(h.w));
      oh[o4] = h;
      ol[o4] = l;
    }
  }
}

// ============ k_gemmF: 64x1024 tile, A fully in LDS (no K-loop barriers) ============
// 16 waves; wave w owns cols [w*64, w*64+64). Fused: q-normalize+write, bmu, colsum psum.
// launch_bounds(1024, 8): 2 blocks/CU (LDS-capped anyway), reg budget 256/thread.
__global__ __launch_bounds__(1024, 8) void k_gemmF(
    const ushortT* __restrict__ A2, const ushortT* __restrict__ nhiF,
    const ushortT* __restrict__ nloF, const float* __restrict__ zn,
    const float* __restrict__ nnorm, float* __restrict__ qout,
    float* __restrict__ bmuf, float* __restrict__ psum) {
  __shared__ __align__(16) unsigned char sA[65536];  // 64 rows x 512 bf16, swizzled
  __shared__ float srowS[64][16];
  __shared__ u64 sbmu[64][16];
  __shared__ float sinv[64];
  const int tid = threadIdx.x, lane = tid & 63, w = tid >> 6;  // w: 0..15
  const int rl = lane & 15, kq = lane >> 4;
  const long row0 = (long)blockIdx.x * 64;

  // stage A (64 KB) once; source slot pre-XOR'd with (row&7), LDS dest linear
#pragma unroll
  for (int i = 0; i < 4; ++i) {
    const int flat = i * 1024 + tid;
    const int r = flat >> 6, slot = flat & 63;
    const int srcs = slot ^ (r & 7);
    __builtin_amdgcn_global_load_lds(
        (const __attribute__((address_space(1))) void*)(A2 + (row0 + r) * 512 + srcs * 8),
        (__attribute__((address_space(3))) void*)(sA + flat * 16), 16, 0, 0);
  }

  const ushortT* Bh = nhiF + (long)(w * 4) * 4096 + lane * 8;
  const ushortT* Bl = nloF + (long)(w * 4) * 4096 + lane * 8;

  f32x4 acc[4][4];
#pragma unroll
  for (int g = 0; g < 4; ++g)
#pragma unroll
    for (int c = 0; c < 4; ++c) acc[g][c] = (f32x4){0.f, 0.f, 0.f, 0.f};

  __syncthreads();  // A staged

#pragma unroll
  for (int m = 0; m < 24; ++m) {
    const int t3 = m >> 3, ks = m & 7;
    const int abase = (t3 == 2) ? 32 : 0;          // A third: hi,hi,lo
    const ushortT* Bp = (t3 == 1) ? Bl : Bh;       // B third: hi,lo,hi
    bf16x8 b[4];
#pragma unroll
    for (int c = 0; c < 4; ++c) b[c] = *(const bf16x8*)(Bp + c * 4096 + ks * 512);
    bf16x8 a[4];
#pragma unroll
    for (int g = 0; g < 4; ++g) {
      const int rr = g * 16 + rl;
      const int kslot = abase + ks * 4 + kq;
      a[g] = *(const bf16x8*)(sA + rr * 1024 + ((kslot ^ (rr & 7)) << 4));
    }
    __builtin_amdgcn_s_setprio(1);
#pragma unroll
    for (int g = 0; g < 4; ++g)
#pragma unroll
      for (int c = 0; c < 4; ++c)
        acc[g][c] = __builtin_amdgcn_mfma_f32_16x16x32_bf16(a[g], b[c], acc[g][c], 0, 0, 0);
    __builtin_amdgcn_s_setprio(0);
  }

  // ---- epilogue: dist -> q, row sums + argmin across 16 waves ----
  float nnv[4];
#pragma unroll
  for (int c = 0; c < 4; ++c) nnv[c] = nnorm[w * 64 + c * 16 + rl];

  float rs[4][4];
  u64 bm[4][4];
#pragma unroll
  for (int g = 0; g < 4; ++g)
#pragma unroll
    for (int r = 0; r < 4; ++r) { rs[g][r] = 0.f; bm[g][r] = ~0ull; }

#pragma unroll
  for (int g = 0; g < 4; ++g) {
    float znv[4];
#pragma unroll
    for (int r = 0; r < 4; ++r) znv[r] = zn[row0 + g * 16 + kq * 4 + r];
#pragma unroll
    for (int c = 0; c < 4; ++c)
#pragma unroll
      for (int r = 0; r < 4; ++r) {
        const float dot = acc[g][c][r];
        const float d2 = znv[r] + nnv[c] - 2.f * dot;
        const float dist = sqrtf(fmaxf(d2, 0.f));
        const float qv = 1.f / (1.f + dist);
        acc[g][c][r] = qv;
        rs[g][r] += qv;
        const int col = w * 64 + c * 16 + rl;
        const u64 pk = ((u64)__float_as_uint(dist) << 32) | (unsigned int)col;
        bm[g][r] = pk < bm[g][r] ? pk : bm[g][r];
      }
  }
#pragma unroll
  for (int g = 0; g < 4; ++g)
#pragma unroll
    for (int r = 0; r < 4; ++r) {
#pragma unroll
      for (int m = 1; m < 16; m <<= 1) {
        rs[g][r] += __shfl_xor(rs[g][r], m, 64);
        const u64 o = __shfl_xor(bm[g][r], m, 64);
        bm[g][r] = o < bm[g][r] ? o : bm[g][r];
      }
      if (rl == 0) {
        srowS[g * 16 + kq * 4 + r][w] = rs[g][r];
        sbmu[g * 16 + kq * 4 + r][w] = bm[g][r];
      }
    }
  __syncthreads();
  if (tid < 64) {
    float s = 0.f;
    u64 best = ~0ull;
#pragma unroll
    for (int i = 0; i < 16; ++i) {
      s += srowS[tid][i];
      const u64 v = sbmu[tid][i];
      best = v < best ? v : best;
    }
    sinv[tid] = 1.f / s;
    bmuf[row0 + tid] = (float)(int)(unsigned int)(best & 0xffffffffull);
  }
  __syncthreads();

  // ---- normalize + store q (scalar dwords) + colsum partials (no atomics) ----
  float cp[4];
#pragma unroll
  for (int c = 0; c < 4; ++c) cp[c] = 0.f;
#pragma unroll
  for (int g = 0; g < 4; ++g) {
    float inv[4];
#pragma unroll
    for (int r = 0; r < 4; ++r) inv[r] = sinv[g * 16 + kq * 4 + r];
#pragma unroll
    for (int c = 0; c < 4; ++c)
#pragma unroll
      for (int r = 0; r < 4; ++r) {
        const float qn = acc[g][c][r] * inv[r];
        qout[(row0 + g * 16 + kq * 4 + r) * Nn + w * 64 + c * 16 + rl] = qn;
        cp[c] = fmaf(qn, qn, cp[c]);
      }
  }
#pragma unroll
  for (int c = 0; c < 4; ++c) {
    cp[c] += __shfl_xor(cp[c], 16, 64);
    cp[c] += __shfl_xor(cp[c], 32, 64);
    if (kq == 0) psum[(long)blockIdx.x * Nn + w * 64 + c * 16 + rl] = cp[c];
  }
}

// ---- reduce psum[512][1024] -> colsum ----
__global__ __launch_bounds__(256) void k_cs(const float* __restrict__ psum,
                                            float* __restrict__ colsum) {
  __shared__ float sh[4][64];
  const int c = threadIdx.x & 63, sl = threadIdx.x >> 6;
  const int col = blockIdx.x * 64 + c;
  float s = 0.f;
#pragma unroll 4
  for (int p = sl * 128; p < sl * 128 + 128; ++p) s += psum[(long)p * Nn + col];
  sh[sl][c] = s;
  __syncthreads();
  if (sl == 0) colsum[col] = sh[0][c] + sh[1][c] + sh[2][c] + sh[3][c];
}

// ============ k_tail: [0,2048) KL | [2048,4096) som+nb | [4096,4352) diversity ============
__global__ __launch_bounds__(256) void k_tail(
    const float* __restrict__ q, const float* __restrict__ colsum,
    const float* __restrict__ z, const float* __restrict__ nodes,
    const float* __restrict__ bmuf, const ushortT* __restrict__ nhiF,
    const ushortT* __restrict__ nloF, const float* __restrict__ nnorm,
    float* __restrict__ som, float* __restrict__ scal) {
  __shared__ float sh[2052];
  const int tid = threadIdx.x, lane = tid & 63, wave = tid >> 6;
  const int bid = blockIdx.x;
  if (bid < 2048) {
    // ---- KL ----
    float* rcs = sh;
    float* lcs = sh + 1024;
    float* sb = sh + 2048;
#pragma unroll
    for (int j = 0; j < 4; ++j) {
      const float cs = colsum[tid + 256 * j];
      rcs[tid + 256 * j] = 1.f / cs;
      lcs[tid + 256 * j] = __logf(cs);
    }
    __syncthreads();
    const long r0 = (long)bid * 16;
    float klp = 0.f;
    for (int rr = 0; rr < 4; ++rr) {
      const long row = r0 + rr * 4 + wave;
      float s = 0.f, a = 0.f;
#pragma unroll
      for (int j = 0; j < 16; ++j) {
        const int col = lane + 64 * j;
        const float t = q[row * Nn + col];
        const float u = t * t * rcs[col];
        s += u;
        a = fmaf(u, __logf(t) - lcs[col], a);
      }
#pragma unroll
      for (int o = 1; o < 64; o <<= 1) {
        s += __shfl_xor(s, o, 64);
        a += __shfl_xor(a, o, 64);
      }
      if (lane == 0) klp += a / s - __logf(s);
    }
    const float tot = block_reduce_sum(klp, sb);
    if (tid == 0) atomicAdd(&scal[0], tot);
  } else if (bid < 4096) {
    // ---- som_z + time smooth + neighbor ----
    float* sb = sh;
    const long r0 = (long)(bid - 2048) * 16;
    float ts = 0.f, zp = 0.f;
    if ((r0 & (Tt - 1)) > 0) zp = z[(r0 - 1) * Dd + tid];
    for (int r = 0; r < 16; ++r) {
      const long row = r0 + r;
      const float zc = z[row * Dd + tid];
      const int bi = (int)bmuf[row];
      const float nv = nodes[(long)bi * Dd + tid];
      som[row * Dd + tid] = zc + 0.1f * (nv - zc);
      if ((row & (Tt - 1)) > 0) {
        const float dd = zc - zp;
        ts = fmaf(dd, dd, ts);
      }
      zp = zc;
    }
    const float tts = block_reduce_sum(ts, sb);
    if (tid == 0) atomicAdd(&scal[2], tts);
    float nbv = 0.f;
    if (tid < 16) {
      const long row = r0 + tid;
      if ((row & (Tt - 1)) != (Tt - 1)) {
        const int b1 = (int)bmuf[row], b2 = (int)bmuf[row + 1];
        nbv = (float)(abs((b1 >> 5) - (b2 >> 5)) + abs((b1 & 31) - (b2 & 31)));
      }
    }
    __syncthreads();
    const float tnb = block_reduce_sum(nbv, sb);
    if (tid == 0) atomicAdd(&scal[3], tnb);
  } else {
    // ---- diversity via node fragments ----
    float* sb = sh;
    const int w = wave;
    const int rl = lane & 15, kq = lane >> 4;
    const int bi = (bid - 4096) & 63;
    const int cq = (bid - 4096) >> 6;
    const int lo8 = lane * 8;
    f32x4 acc[4];
#pragma unroll
    for (int c = 0; c < 4; ++c) acc[c] = (f32x4){0.f, 0.f, 0.f, 0.f};
#pragma unroll 2
    for (int ks = 0; ks < 8; ++ks) {
      const bf16x8 ah = *(const bf16x8*)(nhiF + (long)bi * 4096 + ks * 512 + lo8);
      const bf16x8 al = *(const bf16x8*)(nloF + (long)bi * 4096 + ks * 512 + lo8);
#pragma unroll
      for (int c = 0; c < 4; ++c) {
        const long ct = (long)(cq * 16 + w * 4 + c);
        const bf16x8 bh = *(const bf16x8*)(nhiF + ct * 4096 + ks * 512 + lo8);
        const bf16x8 bl = *(const bf16x8*)(nloF + ct * 4096 + ks * 512 + lo8);
        acc[c] = __builtin_amdgcn_mfma_f32_16x16x32_bf16(ah, bh, acc[c], 0, 0, 0);
        acc[c] = __builtin_amdgcn_mfma_f32_16x16x32_bf16(ah, bl, acc[c], 0, 0, 0);
        acc[c] = __builtin_amdgcn_mfma_f32_16x16x32_bf16(al, bh, acc[c], 0, 0, 0);
      }
    }
    float ni[4];
#pragma unroll
    for (int r = 0; r < 4; ++r) ni[r] = nnorm[bi * 16 + kq * 4 + r];
    float dsum = 0.f;
#pragma unroll
    for (int c = 0; c < 4; ++c) {
      const float nj = nnorm[(cq * 16 + w * 4 + c) * 16 + rl];
#pragma unroll
      for (int r = 0; r < 4; ++r) {
        const float d2 = ni[r] + nj - 2.f * acc[c][r];
        dsum += sqrtf(fmaxf(d2, 0.f));
      }
    }
    const float tot = block_reduce_sum(dsum, sb);
    if (tid == 0) atomicAdd(&scal[1], tot);
  }
}

// ---- final scalars ----
__global__ void k_final(const float* __restrict__ scal, float* __restrict__ o) {
  const float kl = scal[0] * (1.f / 32768.f);
  const float dv = -scal[1] * (1.f / (1024.f * 1024.f));
  const float ts = scal[2] * (0.9f / (64.f * 511.f * 256.f));
  const float nb = scal[3] * (1.f / 32704.f);
  o[0] = kl + 0.5f * dv + 0.3f * ts + 0.2f * nb;
  o[1] = kl;
  o[2] = dv;
  o[3] = ts;
  o[4] = nb;
}

// ================= fallback (fp32 path, small ws) =================
__global__ __launch_bounds__(256) void k_prep_fb(const float* __restrict__ nodes,
                                                 float* __restrict__ nt,
                                                 float* __restrict__ nnorm) {
  __shared__ float sb[4];
  const int j = blockIdx.x, d = threadIdx.x;
  const float v = nodes[j * Dd + d];
  nt[(long)d * Nn + j] = v;
  const float tot = block_reduce_sum(v * v, sb);
  if (threadIdx.x == 0) nnorm[j] = tot;
}

__global__ __launch_bounds__(256) void k_div_fb(const float* __restrict__ nodes,
                                                const float* __restrict__ nt,
                                                const float* __restrict__ nnorm,
                                                float* __restrict__ scal) {
  __shared__ float ni[4][Dd];
  __shared__ float sb[4];
  const int tid = threadIdx.x;
  const int i0 = blockIdx.x * 4;
#pragma unroll
  for (int r = 0; r < 4; ++r) ni[r][tid] = nodes[(i0 + r) * Dd + tid];
  __syncthreads();
  float acc[4][4];
#pragma unroll
  for (int r = 0; r < 4; ++r)
#pragma unroll
    for (int jj = 0; jj < 4; ++jj) acc[r][jj] = 0.f;
  for (int d = 0; d < Dd; ++d) {
    float nj[4];
#pragma unroll
    for (int jj = 0; jj < 4; ++jj) nj[jj] = nt[(long)d * Nn + tid + 256 * jj];
#pragma unroll
    for (int r = 0; r < 4; ++r) {
      const float s = ni[r][d];
#pragma unroll
      for (int jj = 0; jj < 4; ++jj) acc[r][jj] = fmaf(s, nj[jj], acc[r][jj]);
    }
  }
  float sum = 0.f;
#pragma unroll
  for (int r = 0; r < 4; ++r)
#pragma unroll
    for (int jj = 0; jj < 4; ++jj) {
      const float d2 = nnorm[i0 + r] + nnorm[tid + 256 * jj] - 2.f * acc[r][jj];
      sum += sqrtf(fmaxf(d2, 0.f));
    }
  const float tot = block_reduce_sum(sum, sb);
  if (tid == 0) atomicAdd(&scal[1], tot);
}

__global__ __launch_bounds__(256) void k_dist_fb(
    const float* __restrict__ z, const float* __restrict__ nt,
    const float* __restrict__ nnorm, float* __restrict__ qout,
    float* __restrict__ srow, float* __restrict__ bmuf) {
  __shared__ float zt[Dd][65];
  __shared__ float rs4[4][64];
  __shared__ u64 cand[4][64];
  const int tid = threadIdx.x, lane = tid & 63, wave = tid >> 6;
  const long row0 = (long)blockIdx.x * 64;
  for (int k = 0; k < 64; ++k) {
    const int t = (int)((row0 + k) & (Tt - 1));
    const float tw = powf(0.9f, (float)(Tt - 1 - t));
    zt[tid][k] = z[(row0 + k) * Dd + tid] * tw;
  }
  __syncthreads();
  float zns = 0.f;
  for (int d = 0; d < Dd; ++d) {
    const float v = zt[d][lane];
    zns = fmaf(v, v, zns);
  }
  const long myrow = row0 + lane;
  float rsum = 0.f;
  u64 best = ~0ull;
  const int j0w = wave * 256;
  for (int chunk = 0; chunk < 16; ++chunk) {
    const int j0 = j0w + chunk * 16;
    float acc[16];
#pragma unroll
    for (int i = 0; i < 16; ++i) acc[i] = 0.f;
    const float* ntp = nt + j0;
    for (int d = 0; d < Dd; ++d) {
      const float zv = zt[d][lane];
      const float4 a = ((const float4*)ntp)[0];
      const float4 b = ((const float4*)ntp)[1];
      const float4 c = ((const float4*)ntp)[2];
      const float4 e = ((const float4*)ntp)[3];
      ntp += Nn;
      acc[0] = fmaf(zv, a.x, acc[0]); acc[1] = fmaf(zv, a.y, acc[1]);
      acc[2] = fmaf(zv, a.z, acc[2]); acc[3] = fmaf(zv, a.w, acc[3]);
      acc[4] = fmaf(zv, b.x, acc[4]); acc[5] = fmaf(zv, b.y, acc[5]);
      acc[6] = fmaf(zv, b.z, acc[6]); acc[7] = fmaf(zv, b.w, acc[7]);
      acc[8] = fmaf(zv, c.x, acc[8]); acc[9] = fmaf(zv, c.y, acc[9]);
      acc[10] = fmaf(zv, c.z, acc[10]); acc[11] = fmaf(zv, c.w, acc[11]);
      acc[12] = fmaf(zv, e.x, acc[12]); acc[13] = fmaf(zv, e.y, acc[13]);
      acc[14] = fmaf(zv, e.z, acc[14]); acc[15] = fmaf(zv, e.w, acc[15]);
    }
#pragma unroll
    for (int jj = 0; jj < 16; ++jj) {
      const int j = j0 + jj;
      const float d2 = zns + nnorm[j] - 2.f * acc[jj];
      const float dist = sqrtf(fmaxf(d2, 0.f));
      const float qr = 1.f / (1.f + dist);
      qout[myrow * Nn + j] = qr;
      rsum += qr;
      const u64 pk = ((u64)__float_as_uint(dist) << 32) | (unsigned int)j;
      best = pk < best ? pk : best;
    }
  }
  rs4[wave][lane] = rsum;
  cand[wave][lane] = best;
  __syncthreads();
  if (wave == 0) {
    const float s = rs4[0][lane] + rs4[1][lane] + rs4[2][lane] + rs4[3][lane];
    srow[myrow] = s;
    const u64 m0 = cand[0][lane] < cand[1][lane] ? cand[0][lane] : cand[1][lane];
    const u64 m1 = cand[2][lane] < cand[3][lane] ? cand[2][lane] : cand[3][lane];
    const u64 m = m0 < m1 ? m0 : m1;
    bmuf[myrow] = (float)(int)(unsigned int)(m & 0xffffffffull);
  }
}

__global__ __launch_bounds__(256) void k_norm_fb(float* __restrict__ q,
                                                 const float* __restrict__ srow,
                                                 float* __restrict__ colsum) {
  const int tid = threadIdx.x;
  const long r0 = (long)blockIdx.x * 16;
  float cs[4] = {0.f, 0.f, 0.f, 0.f};
  for (int r = 0; r < 16; ++r) {
    const long row = r0 + r;
    const float inv = 1.f / srow[row];
#pragma unroll
    for (int j = 0; j < 4; ++j) {
      const long idx = row * Nn + tid + 256 * j;
      const float v = q[idx] * inv;
      q[idx] = v;
      cs[j] = fmaf(v, v, cs[j]);
    }
  }
#pragma unroll
  for (int j = 0; j < 4; ++j) atomicAdd(&colsum[tid + 256 * j], cs[j]);
}

__global__ __launch_bounds__(256) void k_kl_fb(const float* __restrict__ q,
                                               const float* __restrict__ colsum,
                                               float* __restrict__ scal) {
  __shared__ float rcs[Nn];
  __shared__ float lcs[Nn];
  __shared__ float sb[4];
  const int tid = threadIdx.x, lane = tid & 63, wave = tid >> 6;
#pragma unroll
  for (int j = 0; j < 4; ++j) {
    const float cs = colsum[tid + 256 * j];
    rcs[tid + 256 * j] = 1.f / cs;
    lcs[tid + 256 * j] = __logf(cs);
  }
  __syncthreads();
  const long r0 = (long)blockIdx.x * 16;
  float klp = 0.f;
  for (int rr = 0; rr < 4; ++rr) {
    const long row = r0 + rr * 4 + wave;
    float s = 0.f, a = 0.f;
#pragma unroll
    for (int j = 0; j < 16; ++j) {
      const int col = lane + 64 * j;
      const float t = q[row * Nn + col];
      const float u = t * t * rcs[col];
      s += u;
      a = fmaf(u, __logf(t) - lcs[col], a);
    }
#pragma unroll
    for (int o = 1; o < 64; o <<= 1) {
      s += __shfl_xor(s, o, 64);
      a += __shfl_xor(a, o, 64);
    }
    if (lane == 0) klp += a / s - __logf(s);
  }
  const float tot = block_reduce_sum(klp, sb);
  if (tid == 0) atomicAdd(&scal[0], tot);
}

__global__ __launch_bounds__(256) void k_somnb_fb(const float* __restrict__ z,
                                                  const float* __restrict__ nodes,
                                                  const float* __restrict__ bmuf,
                                                  float* __restrict__ som,
                                                  float* __restrict__ scal) {
  __shared__ float sb[4];
  const int tid = threadIdx.x;
  const long r0 = (long)blockIdx.x * 16;
  float ts = 0.f, zp = 0.f;
  if ((r0 & (Tt - 1)) > 0) zp = z[(r0 - 1) * Dd + tid];
  for (int r = 0; r < 16; ++r) {
    const long row = r0 + r;
    const float zc = z[row * Dd + tid];
    const int bi = (int)bmuf[row];
    const float nv = nodes[(long)bi * Dd + tid];
    som[row * Dd + tid] = zc + 0.1f * (nv - zc);
    if ((row & (Tt - 1)) > 0) {
      const float dd = zc - zp;
      ts = fmaf(dd, dd, ts);
    }
    zp = zc;
  }
  const float tts = block_reduce_sum(ts, sb);
  if (tid == 0) atomicAdd(&scal[2], tts);
  float nbv = 0.f;
  if (tid < 16) {
    const long row = r0 + tid;
    if ((row & (Tt - 1)) != (Tt - 1)) {
      const int b1 = (int)bmuf[row], b2 = (int)bmuf[row + 1];
      nbv = (float)(abs((b1 >> 5) - (b2 >> 5)) + abs((b1 & 31) - (b2 & 31)));
    }
  }
  __syncthreads();
  const float tnb = block_reduce_sum(nbv, sb);
  if (tid == 0) atomicAdd(&scal[3], tnb);
}

extern "C" void kernel_launch(void* const* d_in, const int* in_sizes, int n_in,
                              void* d_out, int out_size, void* d_ws, size_t ws_size,
                              hipStream_t stream) {
  const float* z = (const float*)d_in[0];
  const float* nodes = (const float*)d_in[1];
  float* out = (float*)d_out;
  unsigned char* ws = (unsigned char*)d_ws;

  float* som = out + OUT_SOM;
  float* scal_out = out + OUT_SCAL;
  float* qout = out + OUT_Q;
  float* bmuf = out + OUT_BMU;

  const size_t NEED = 36839440;
  if (ws_size >= NEED) {
    ushortT* A2 = (ushortT*)(ws + 0);           // 32 MB row-major [zh|zl]
    ushortT* nhiF = (ushortT*)(ws + 33554432);  // 512 KB fragment
    ushortT* nloF = (ushortT*)(ws + 34078720);  // 512 KB fragment
    float* zn = (float*)(ws + 34603008);        // 128 KB
    float* nnorm = (float*)(ws + 34734080);     // 4 KB
    float* psum = (float*)(ws + 34738176);      // 512 x 1024 f32 = 2 MB
    float* colsum = (float*)(ws + 36835328);    // 4 KB
    float* scal = (float*)(ws + 36839424);      // 16 B

    hipMemsetAsync(scal, 0, 16, stream);

    k_conv3<<<8256, 256, 0, stream>>>(z, nodes, A2, nhiF, nloF, zn, nnorm);
    k_gemmF<<<512, 1024, 0, stream>>>(A2, nhiF, nloF, zn, nnorm, qout, bmuf, psum);
    k_cs<<<16, 256, 0, stream>>>(psum, colsum);
    k_tail<<<4352, 256, 0, stream>>>(qout, colsum, z, nodes, bmuf, nhiF, nloF, nnorm,
                                     som, scal);
    k_final<<<1, 1, 0, stream>>>(scal, scal_out);
  } else {
    float* wsf = (float*)ws;
    float* nt = wsf;
    float* nnorm = wsf + 262144;
    float* srow = wsf + 263168;
    float* colsum = wsf + 295936;
    float* scal = wsf + 296960;

    hipMemsetAsync(colsum, 0, (1024 + 4) * sizeof(float), stream);
    k_prep_fb<<<1024, 256, 0, stream>>>(nodes, nt, nnorm);
    k_div_fb<<<256, 256, 0, stream>>>(nodes, nt, nnorm, scal);
    k_dist_fb<<<512, 256, 0, stream>>>(z, nt, nnorm, qout, srow, bmuf);
    k_norm_fb<<<2048, 256, 0, stream>>>(qout, srow, colsum);
    k_kl_fb<<<2048, 256, 0, stream>>>(qout, colsum, scal);
    k_somnb_fb<<<2048, 256, 0, stream>>>(z, nodes, bmuf, som, scal);
    k_final<<<1, 1, 0, stream>>>(scal, scal_out);
  }
}

// Round 13
// 237.260 us; speedup vs baseline: 4.8750x; 4.8750x over previous
//
#include <hip/hip_runtime.h>
#include <math.h>

#define Bb 64
#define Tt 512
#define Dd 256
#define Nn 1024
#define NROWS 32768

// d_out layout (floats)
#define OUT_SOM 0L
#define OUT_SCAL 8388608L
#define OUT_Q 8388613L
#define OUT_BMU 41943045L

typedef __attribute__((ext_vector_type(8))) short bf16x8;
typedef __attribute__((ext_vector_type(4))) float f32x4;
typedef unsigned long long u64;
typedef unsigned short ushortT;

static __device__ __forceinline__ unsigned short f2bf(float x) {
  unsigned int u = __float_as_uint(x);
  unsigned int r = (u + 0x7fffu + ((u >> 16) & 1u)) >> 16;
  return (unsigned short)r;
}
static __device__ __forceinline__ float bf2f(unsigned short b) {
  return __uint_as_float(((unsigned int)b) << 16);
}

static __device__ __forceinline__ float block_reduce_sum(float v, float* sb) {
#pragma unroll
  for (int o = 32; o > 0; o >>= 1) v += __shfl_down(v, o, 64);
  const int lane = threadIdx.x & 63, w = threadIdx.x >> 6;
  if (lane == 0) sb[w] = v;
  __syncthreads();
  return (threadIdx.x == 0) ? (sb[0] + sb[1] + sb[2] + sb[3]) : 0.0f;
}

// ============ k_conv3: A2 row-major [zh|zl] + node FRAGMENT layout ============
// blocks [0,8192): z rows (wave per row). blocks [8192,8256): node 16-col tiles.
// B-frag per tile ct: idx = ks*512 + k8*128 + c16*8 + e; col=ct*16+c16, k=ks*32+k8*8+e
__global__ __launch_bounds__(256) void k_conv3(
    const float* __restrict__ z, const float* __restrict__ nodes,
    ushortT* __restrict__ A2, ushortT* __restrict__ nhiF, ushortT* __restrict__ nloF,
    float* __restrict__ zn, float* __restrict__ nnorm) {
  __shared__ float sm[32 * 260];
  const int tid = threadIdx.x;
  if (blockIdx.x < 8192) {
    const int lane = tid & 63, w = tid >> 6;
    const long row = (long)blockIdx.x * 4 + w;
    const int t = (int)(row & (Tt - 1));
    const float tw = powf(0.9f, (float)(Tt - 1 - t));
    const float4 v = ((const float4*)(z + row * Dd))[lane];
    float x0 = v.x * tw, x1 = v.y * tw, x2 = v.z * tw, x3 = v.w * tw;
    ushort4 h, l;
    h.x = f2bf(x0); l.x = f2bf(x0 - bf2f(h.x));
    h.y = f2bf(x1); l.y = f2bf(x1 - bf2f(h.y));
    h.z = f2bf(x2); l.z = f2bf(x2 - bf2f(h.z));
    h.w = f2bf(x3); l.w = f2bf(x3 - bf2f(h.w));
    *(ushort4*)(A2 + row * 512 + lane * 4) = h;
    *(ushort4*)(A2 + row * 512 + 256 + lane * 4) = l;
    float s = x0 * x0 + x1 * x1 + x2 * x2 + x3 * x3;
#pragma unroll
    for (int o = 32; o > 0; o >>= 1) s += __shfl_down(s, o, 64);
    if (lane == 0) zn[row] = s;
  } else {
    const int ct = blockIdx.x - 8192;  // 0..63
    const int jr = tid >> 4, cg = tid & 15;
    const long nrow = (long)(ct * 16 + jr);
    float nrm = 0.f;
#pragma unroll
    for (int k = 0; k < 4; ++k) {
      const int c4 = cg + k * 16;
      const float4 v = ((const float4*)(nodes + nrow * Dd))[c4];
      *(float4*)&sm[jr * 260 + c4 * 4] = v;
      nrm += v.x * v.x + v.y * v.y + v.z * v.z + v.w * v.w;
    }
    nrm += __shfl_xor(nrm, 1, 64);
    nrm += __shfl_xor(nrm, 2, 64);
    nrm += __shfl_xor(nrm, 4, 64);
    nrm += __shfl_xor(nrm, 8, 64);
    if (cg == 0) nnorm[nrow] = nrm;
    __syncthreads();
    ushort4* oh = (ushort4*)(nhiF + (long)ct * 4096);
    ushort4* ol = (ushort4*)(nloF + (long)ct * 4096);
#pragma unroll
    for (int i = 0; i < 4; ++i) {
      const int o4 = tid + 256 * i;
      const int e4 = (o4 & 1) * 4;
      const int c16 = (o4 >> 1) & 15;
      const int k8 = (o4 >> 5) & 3;
      const int ks = o4 >> 7;
      const float* p = &sm[c16 * 260 + ks * 32 + k8 * 8 + e4];
      const float4 v = *(const float4*)p;
      ushort4 h, l;
      h.x = f2bf(v.x); l.x = f2bf(v.x - bf2f(h.x));
      h.y = f2bf(v.y); l.y = f2bf(v.y - bf2f(h.y));
      h.z = f2bf(v.z); l.z = f2bf(v.z - bf2f(h.z));
      h.w = f2bf(v.w); l.w = f2bf(v.w - bf2f(h.w));
      oh[o4] = h;
      ol[o4] = l;
    }
  }
}

// ============ k_gemmF: 64x1024 tile, A fully in LDS (no K-loop barriers) ============
// 16 waves; wave w owns cols [w*64, w*64+64). Fused: q-normalize+write, bmu, colsum psum.
__global__ __launch_bounds__(1024) void k_gemmF(
    const ushortT* __restrict__ A2, const ushortT* __restrict__ nhiF,
    const ushortT* __restrict__ nloF, const float* __restrict__ zn,
    const float* __restrict__ nnorm, float* __restrict__ qout,
    float* __restrict__ bmuf, float* __restrict__ psum) {
  __shared__ __align__(16) unsigned char sA[65536];  // 64 rows x 512 bf16, swizzled
  __shared__ float srowS[64][16];
  __shared__ u64 sbmu[64][16];
  __shared__ float sinv[64];
  const int tid = threadIdx.x, lane = tid & 63, w = tid >> 6;  // w: 0..15
  const int rl = lane & 15, kq = lane >> 4;
  const long row0 = (long)blockIdx.x * 64;

  // stage A (64 KB) once; source slot pre-XOR'd with (row&7), LDS dest linear
#pragma unroll
  for (int i = 0; i < 4; ++i) {
    const int flat = i * 1024 + tid;
    const int r = flat >> 6, slot = flat & 63;
    const int srcs = slot ^ (r & 7);
    __builtin_amdgcn_global_load_lds(
        (const __attribute__((address_space(1))) void*)(A2 + (row0 + r) * 512 + srcs * 8),
        (__attribute__((address_space(3))) void*)(sA + flat * 16), 16, 0, 0);
  }

  const ushortT* Bh = nhiF + (long)(w * 4) * 4096 + lane * 8;
  const ushortT* Bl = nloF + (long)(w * 4) * 4096 + lane * 8;

  f32x4 acc[4][4];
#pragma unroll
  for (int g = 0; g < 4; ++g)
#pragma unroll
    for (int c = 0; c < 4; ++c) acc[g][c] = (f32x4){0.f, 0.f, 0.f, 0.f};

  __syncthreads();  // A staged

#pragma unroll
  for (int m = 0; m < 24; ++m) {
    const int t3 = m >> 3, ks = m & 7;
    const int abase = (t3 == 2) ? 32 : 0;          // A third: hi,hi,lo
    const ushortT* Bp = (t3 == 1) ? Bl : Bh;       // B third: hi,lo,hi
    bf16x8 b[4];
#pragma unroll
    for (int c = 0; c < 4; ++c) b[c] = *(const bf16x8*)(Bp + c * 4096 + ks * 512);
    bf16x8 a[4];
#pragma unroll
    for (int g = 0; g < 4; ++g) {
      const int rr = g * 16 + rl;
      const int kslot = abase + ks * 4 + kq;
      a[g] = *(const bf16x8*)(sA + rr * 1024 + ((kslot ^ (rr & 7)) << 4));
    }
    __builtin_amdgcn_s_setprio(1);
#pragma unroll
    for (int g = 0; g < 4; ++g)
#pragma unroll
      for (int c = 0; c < 4; ++c)
        acc[g][c] = __builtin_amdgcn_mfma_f32_16x16x32_bf16(a[g], b[c], acc[g][c], 0, 0, 0);
    __builtin_amdgcn_s_setprio(0);
  }

  // ---- epilogue: dist -> q, row sums + argmin across 16 waves ----
  float nnv[4];
#pragma unroll
  for (int c = 0; c < 4; ++c) nnv[c] = nnorm[w * 64 + c * 16 + rl];

  float rs[4][4];
  u64 bm[4][4];
#pragma unroll
  for (int g = 0; g < 4; ++g)
#pragma unroll
    for (int r = 0; r < 4; ++r) { rs[g][r] = 0.f; bm[g][r] = ~0ull; }

#pragma unroll
  for (int g = 0; g < 4; ++g) {
    float znv[4];
#pragma unroll
    for (int r = 0; r < 4; ++r) znv[r] = zn[row0 + g * 16 + kq * 4 + r];
#pragma unroll
    for (int c = 0; c < 4; ++c)
#pragma unroll
      for (int r = 0; r < 4; ++r) {
        const float dot = acc[g][c][r];
        const float d2 = znv[r] + nnv[c] - 2.f * dot;
        const float dist = sqrtf(fmaxf(d2, 0.f));
        const float qv = 1.f / (1.f + dist);
        acc[g][c][r] = qv;
        rs[g][r] += qv;
        const int col = w * 64 + c * 16 + rl;
        const u64 pk = ((u64)__float_as_uint(dist) << 32) | (unsigned int)col;
        bm[g][r] = pk < bm[g][r] ? pk : bm[g][r];
      }
  }
#pragma unroll
  for (int g = 0; g < 4; ++g)
#pragma unroll
    for (int r = 0; r < 4; ++r) {
#pragma unroll
      for (int m = 1; m < 16; m <<= 1) {
        rs[g][r] += __shfl_xor(rs[g][r], m, 64);
        const u64 o = __shfl_xor(bm[g][r], m, 64);
        bm[g][r] = o < bm[g][r] ? o : bm[g][r];
      }
      if (rl == 0) {
        srowS[g * 16 + kq * 4 + r][w] = rs[g][r];
        sbmu[g * 16 + kq * 4 + r][w] = bm[g][r];
      }
    }
  __syncthreads();
  if (tid < 64) {
    float s = 0.f;
    u64 best = ~0ull;
#pragma unroll
    for (int i = 0; i < 16; ++i) {
      s += srowS[tid][i];
      const u64 v = sbmu[tid][i];
      best = v < best ? v : best;
    }
    sinv[tid] = 1.f / s;
    bmuf[row0 + tid] = (float)(int)(unsigned int)(best & 0xffffffffull);
  }
  __syncthreads();

  // ---- normalize + store q (scalar dwords) + colsum partials (no atomics) ----
  float cp[4];
#pragma unroll
  for (int c = 0; c < 4; ++c) cp[c] = 0.f;
#pragma unroll
  for (int g = 0; g < 4; ++g) {
    float inv[4];
#pragma unroll
    for (int r = 0; r < 4; ++r) inv[r] = sinv[g * 16 + kq * 4 + r];
#pragma unroll
    for (int c = 0; c < 4; ++c)
#pragma unroll
      for (int r = 0; r < 4; ++r) {
        const float qn = acc[g][c][r] * inv[r];
        qout[(row0 + g * 16 + kq * 4 + r) * Nn + w * 64 + c * 16 + rl] = qn;
        cp[c] = fmaf(qn, qn, cp[c]);
      }
  }
#pragma unroll
  for (int c = 0; c < 4; ++c) {
    cp[c] += __shfl_xor(cp[c], 16, 64);
    cp[c] += __shfl_xor(cp[c], 32, 64);
    if (kq == 0) psum[(long)blockIdx.x * Nn + w * 64 + c * 16 + rl] = cp[c];
  }
}

// ---- reduce psum[512][1024] -> colsum ----
__global__ __launch_bounds__(256) void k_cs(const float* __restrict__ psum,
                                            float* __restrict__ colsum) {
  __shared__ float sh[4][64];
  const int c = threadIdx.x & 63, sl = threadIdx.x >> 6;
  const int col = blockIdx.x * 64 + c;
  float s = 0.f;
#pragma unroll 4
  for (int p = sl * 128; p < sl * 128 + 128; ++p) s += psum[(long)p * Nn + col];
  sh[sl][c] = s;
  __syncthreads();
  if (sl == 0) colsum[col] = sh[0][c] + sh[1][c] + sh[2][c] + sh[3][c];
}

// ============ k_tail: [0,2048) KL | [2048,4096) som+nb | [4096,4352) diversity ============
__global__ __launch_bounds__(256) void k_tail(
    const float* __restrict__ q, const float* __restrict__ colsum,
    const float* __restrict__ z, const float* __restrict__ nodes,
    const float* __restrict__ bmuf, const ushortT* __restrict__ nhiF,
    const ushortT* __restrict__ nloF, const float* __restrict__ nnorm,
    float* __restrict__ som, float* __restrict__ scal) {
  __shared__ float sh[2052];
  const int tid = threadIdx.x, lane = tid & 63, wave = tid >> 6;
  const int bid = blockIdx.x;
  if (bid < 2048) {
    // ---- KL ----
    float* rcs = sh;
    float* lcs = sh + 1024;
    float* sb = sh + 2048;
#pragma unroll
    for (int j = 0; j < 4; ++j) {
      const float cs = colsum[tid + 256 * j];
      rcs[tid + 256 * j] = 1.f / cs;
      lcs[tid + 256 * j] = __logf(cs);
    }
    __syncthreads();
    const long r0 = (long)bid * 16;
    float klp = 0.f;
    for (int rr = 0; rr < 4; ++rr) {
      const long row = r0 + rr * 4 + wave;
      float s = 0.f, a = 0.f;
#pragma unroll
      for (int j = 0; j < 16; ++j) {
        const int col = lane + 64 * j;
        const float t = q[row * Nn + col];
        const float u = t * t * rcs[col];
        s += u;
        a = fmaf(u, __logf(t) - lcs[col], a);
      }
#pragma unroll
      for (int o = 1; o < 64; o <<= 1) {
        s += __shfl_xor(s, o, 64);
        a += __shfl_xor(a, o, 64);
      }
      if (lane == 0) klp += a / s - __logf(s);
    }
    const float tot = block_reduce_sum(klp, sb);
    if (tid == 0) atomicAdd(&scal[0], tot);
  } else if (bid < 4096) {
    // ---- som_z + time smooth + neighbor ----
    float* sb = sh;
    const long r0 = (long)(bid - 2048) * 16;
    float ts = 0.f, zp = 0.f;
    if ((r0 & (Tt - 1)) > 0) zp = z[(r0 - 1) * Dd + tid];
    for (int r = 0; r < 16; ++r) {
      const long row = r0 + r;
      const float zc = z[row * Dd + tid];
      const int bi = (int)bmuf[row];
      const float nv = nodes[(long)bi * Dd + tid];
      som[row * Dd + tid] = zc + 0.1f * (nv - zc);
      if ((row & (Tt - 1)) > 0) {
        const float dd = zc - zp;
        ts = fmaf(dd, dd, ts);
      }
      zp = zc;
    }
    const float tts = block_reduce_sum(ts, sb);
    if (tid == 0) atomicAdd(&scal[2], tts);
    float nbv = 0.f;
    if (tid < 16) {
      const long row = r0 + tid;
      if ((row & (Tt - 1)) != (Tt - 1)) {
        const int b1 = (int)bmuf[row], b2 = (int)bmuf[row + 1];
        nbv = (float)(abs((b1 >> 5) - (b2 >> 5)) + abs((b1 & 31) - (b2 & 31)));
      }
    }
    __syncthreads();
    const float tnb = block_reduce_sum(nbv, sb);
    if (tid == 0) atomicAdd(&scal[3], tnb);
  } else {
    // ---- diversity via node fragments ----
    float* sb = sh;
    const int w = wave;
    const int rl = lane & 15, kq = lane >> 4;
    const int bi = (bid - 4096) & 63;
    const int cq = (bid - 4096) >> 6;
    const int lo8 = lane * 8;
    f32x4 acc[4];
#pragma unroll
    for (int c = 0; c < 4; ++c) acc[c] = (f32x4){0.f, 0.f, 0.f, 0.f};
#pragma unroll 2
    for (int ks = 0; ks < 8; ++ks) {
      const bf16x8 ah = *(const bf16x8*)(nhiF + (long)bi * 4096 + ks * 512 + lo8);
      const bf16x8 al = *(const bf16x8*)(nloF + (long)bi * 4096 + ks * 512 + lo8);
#pragma unroll
      for (int c = 0; c < 4; ++c) {
        const long ct = (long)(cq * 16 + w * 4 + c);
        const bf16x8 bh = *(const bf16x8*)(nhiF + ct * 4096 + ks * 512 + lo8);
        const bf16x8 bl = *(const bf16x8*)(nloF + ct * 4096 + ks * 512 + lo8);
        acc[c] = __builtin_amdgcn_mfma_f32_16x16x32_bf16(ah, bh, acc[c], 0, 0, 0);
        acc[c] = __builtin_amdgcn_mfma_f32_16x16x32_bf16(ah, bl, acc[c], 0, 0, 0);
        acc[c] = __builtin_amdgcn_mfma_f32_16x16x32_bf16(al, bh, acc[c], 0, 0, 0);
      }
    }
    float ni[4];
#pragma unroll
    for (int r = 0; r < 4; ++r) ni[r] = nnorm[bi * 16 + kq * 4 + r];
    float dsum = 0.f;
#pragma unroll
    for (int c = 0; c < 4; ++c) {
      const float nj = nnorm[(cq * 16 + w * 4 + c) * 16 + rl];
#pragma unroll
      for (int r = 0; r < 4; ++r) {
        const float d2 = ni[r] + nj - 2.f * acc[c][r];
        dsum += sqrtf(fmaxf(d2, 0.f));
      }
    }
    const float tot = block_reduce_sum(dsum, sb);
    if (tid == 0) atomicAdd(&scal[1], tot);
  }
}

// ---- final scalars ----
__global__ void k_final(const float* __restrict__ scal, float* __restrict__ o) {
  const float kl = scal[0] * (1.f / 32768.f);
  const float dv = -scal[1] * (1.f / (1024.f * 1024.f));
  const float ts = scal[2] * (0.9f / (64.f * 511.f * 256.f));
  const float nb = scal[3] * (1.f / 32704.f);
  o[0] = kl + 0.5f * dv + 0.3f * ts + 0.2f * nb;
  o[1] = kl;
  o[2] = dv;
  o[3] = ts;
  o[4] = nb;
}

// ================= fallback (fp32 path, small ws) =================
__global__ __launch_bounds__(256) void k_prep_fb(const float* __restrict__ nodes,
                                                 float* __restrict__ nt,
                                                 float* __restrict__ nnorm) {
  __shared__ float sb[4];
  const int j = blockIdx.x, d = threadIdx.x;
  const float v = nodes[j * Dd + d];
  nt[(long)d * Nn + j] = v;
  const float tot = block_reduce_sum(v * v, sb);
  if (threadIdx.x == 0) nnorm[j] = tot;
}

__global__ __launch_bounds__(256) void k_div_fb(const float* __restrict__ nodes,
                                                const float* __restrict__ nt,
                                                const float* __restrict__ nnorm,
                                                float* __restrict__ scal) {
  __shared__ float ni[4][Dd];
  __shared__ float sb[4];
  const int tid = threadIdx.x;
  const int i0 = blockIdx.x * 4;
#pragma unroll
  for (int r = 0; r < 4; ++r) ni[r][tid] = nodes[(i0 + r) * Dd + tid];
  __syncthreads();
  float acc[4][4];
#pragma unroll
  for (int r = 0; r < 4; ++r)
#pragma unroll
    for (int jj = 0; jj < 4; ++jj) acc[r][jj] = 0.f;
  for (int d = 0; d < Dd; ++d) {
    float nj[4];
#pragma unroll
    for (int jj = 0; jj < 4; ++jj) nj[jj] = nt[(long)d * Nn + tid + 256 * jj];
#pragma unroll
    for (int r = 0; r < 4; ++r) {
      const float s = ni[r][d];
#pragma unroll
      for (int jj = 0; jj < 4; ++jj) acc[r][jj] = fmaf(s, nj[jj], acc[r][jj]);
    }
  }
  float sum = 0.f;
#pragma unroll
  for (int r = 0; r < 4; ++r)
#pragma unroll
    for (int jj = 0; jj < 4; ++jj) {
      const float d2 = nnorm[i0 + r] + nnorm[tid + 256 * jj] - 2.f * acc[r][jj];
      sum += sqrtf(fmaxf(d2, 0.f));
    }
  const float tot = block_reduce_sum(sum, sb);
  if (tid == 0) atomicAdd(&scal[1], tot);
}

__global__ __launch_bounds__(256) void k_dist_fb(
    const float* __restrict__ z, const float* __restrict__ nt,
    const float* __restrict__ nnorm, float* __restrict__ qout,
    float* __restrict__ srow, float* __restrict__ bmuf) {
  __shared__ float zt[Dd][65];
  __shared__ float rs4[4][64];
  __shared__ u64 cand[4][64];
  const int tid = threadIdx.x, lane = tid & 63, wave = tid >> 6;
  const long row0 = (long)blockIdx.x * 64;
  for (int k = 0; k < 64; ++k) {
    const int t = (int)((row0 + k) & (Tt - 1));
    const float tw = powf(0.9f, (float)(Tt - 1 - t));
    zt[tid][k] = z[(row0 + k) * Dd + tid] * tw;
  }
  __syncthreads();
  float zns = 0.f;
  for (int d = 0; d < Dd; ++d) {
    const float v = zt[d][lane];
    zns = fmaf(v, v, zns);
  }
  const long myrow = row0 + lane;
  float rsum = 0.f;
  u64 best = ~0ull;
  const int j0w = wave * 256;
  for (int chunk = 0; chunk < 16; ++chunk) {
    const int j0 = j0w + chunk * 16;
    float acc[16];
#pragma unroll
    for (int i = 0; i < 16; ++i) acc[i] = 0.f;
    const float* ntp = nt + j0;
    for (int d = 0; d < Dd; ++d) {
      const float zv = zt[d][lane];
      const float4 a = ((const float4*)ntp)[0];
      const float4 b = ((const float4*)ntp)[1];
      const float4 c = ((const float4*)ntp)[2];
      const float4 e = ((const float4*)ntp)[3];
      ntp += Nn;
      acc[0] = fmaf(zv, a.x, acc[0]); acc[1] = fmaf(zv, a.y, acc[1]);
      acc[2] = fmaf(zv, a.z, acc[2]); acc[3] = fmaf(zv, a.w, acc[3]);
      acc[4] = fmaf(zv, b.x, acc[4]); acc[5] = fmaf(zv, b.y, acc[5]);
      acc[6] = fmaf(zv, b.z, acc[6]); acc[7] = fmaf(zv, b.w, acc[7]);
      acc[8] = fmaf(zv, c.x, acc[8]); acc[9] = fmaf(zv, c.y, acc[9]);
      acc[10] = fmaf(zv, c.z, acc[10]); acc[11] = fmaf(zv, c.w, acc[11]);
      acc[12] = fmaf(zv, e.x, acc[12]); acc[13] = fmaf(zv, e.y, acc[13]);
      acc[14] = fmaf(zv, e.z, acc[14]); acc[15] = fmaf(zv, e.w, acc[15]);
    }
#pragma unroll
    for (int jj = 0; jj < 16; ++jj) {
      const int j = j0 + jj;
      const float d2 = zns + nnorm[j] - 2.f * acc[jj];
      const float dist = sqrtf(fmaxf(d2, 0.f));
      const float qr = 1.f / (1.f + dist);
      qout[myrow * Nn + j] = qr;
      rsum += qr;
      const u64 pk = ((u64)__float_as_uint(dist) << 32) | (unsigned int)j;
      best = pk < best ? pk : best;
    }
  }
  rs4[wave][lane] = rsum;
  cand[wave][lane] = best;
  __syncthreads();
  if (wave == 0) {
    const float s = rs4[0][lane] + rs4[1][lane] + rs4[2][lane] + rs4[3][lane];
    srow[myrow] = s;
    const u64 m0 = cand[0][lane] < cand[1][lane] ? cand[0][lane] : cand[1][lane];
    const u64 m1 = cand[2][lane] < cand[3][lane] ? cand[2][lane] : cand[3][lane];
    const u64 m = m0 < m1 ? m0 : m1;
    bmuf[myrow] = (float)(int)(unsigned int)(m & 0xffffffffull);
  }
}

__global__ __launch_bounds__(256) void k_norm_fb(float* __restrict__ q,
                                                 const float* __restrict__ srow,
                                                 float* __restrict__ colsum) {
  const int tid = threadIdx.x;
  const long r0 = (long)blockIdx.x * 16;
  float cs[4] = {0.f, 0.f, 0.f, 0.f};
  for (int r = 0; r < 16; ++r) {
    const long row = r0 + r;
    const float inv = 1.f / srow[row];
#pragma unroll
    for (int j = 0; j < 4; ++j) {
      const long idx = row * Nn + tid + 256 * j;
      const float v = q[idx] * inv;
      q[idx] = v;
      cs[j] = fmaf(v, v, cs[j]);
    }
  }
#pragma unroll
  for (int j = 0; j < 4; ++j) atomicAdd(&colsum[tid + 256 * j], cs[j]);
}

__global__ __launch_bounds__(256) void k_kl_fb(const float* __restrict__ q,
                                               const float* __restrict__ colsum,
                                               float* __restrict__ scal) {
  __shared__ float rcs[Nn];
  __shared__ float lcs[Nn];
  __shared__ float sb[4];
  const int tid = threadIdx.x, lane = tid & 63, wave = tid >> 6;
#pragma unroll
  for (int j = 0; j < 4; ++j) {
    const float cs = colsum[tid + 256 * j];
    rcs[tid + 256 * j] = 1.f / cs;
    lcs[tid + 256 * j] = __logf(cs);
  }
  __syncthreads();
  const long r0 = (long)blockIdx.x * 16;
  float klp = 0.f;
  for (int rr = 0; rr < 4; ++rr) {
    const long row = r0 + rr * 4 + wave;
    float s = 0.f, a = 0.f;
#pragma unroll
    for (int j = 0; j < 16; ++j) {
      const int col = lane + 64 * j;
      const float t = q[row * Nn + col];
      const float u = t * t * rcs[col];
      s += u;
      a = fmaf(u, __logf(t) - lcs[col], a);
    }
#pragma unroll
    for (int o = 1; o < 64; o <<= 1) {
      s += __shfl_xor(s, o, 64);
      a += __shfl_xor(a, o, 64);
    }
    if (lane == 0) klp += a / s - __logf(s);
  }
  const float tot = block_reduce_sum(klp, sb);
  if (tid == 0) atomicAdd(&scal[0], tot);
}

__global__ __launch_bounds__(256) void k_somnb_fb(const float* __restrict__ z,
                                                  const float* __restrict__ nodes,
                                                  const float* __restrict__ bmuf,
                                                  float* __restrict__ som,
                                                  float* __restrict__ scal) {
  __shared__ float sb[4];
  const int tid = threadIdx.x;
  const long r0 = (long)blockIdx.x * 16;
  float ts = 0.f, zp = 0.f;
  if ((r0 & (Tt - 1)) > 0) zp = z[(r0 - 1) * Dd + tid];
  for (int r = 0; r < 16; ++r) {
    const long row = r0 + r;
    const float zc = z[row * Dd + tid];
    const int bi = (int)bmuf[row];
    const float nv = nodes[(long)bi * Dd + tid];
    som[row * Dd + tid] = zc + 0.1f * (nv - zc);
    if ((row & (Tt - 1)) > 0) {
      const float dd = zc - zp;
      ts = fmaf(dd, dd, ts);
    }
    zp = zc;
  }
  const float tts = block_reduce_sum(ts, sb);
  if (tid == 0) atomicAdd(&scal[2], tts);
  float nbv = 0.f;
  if (tid < 16) {
    const long row = r0 + tid;
    if ((row & (Tt - 1)) != (Tt - 1)) {
      const int b1 = (int)bmuf[row], b2 = (int)bmuf[row + 1];
      nbv = (float)(abs((b1 >> 5) - (b2 >> 5)) + abs((b1 & 31) - (b2 & 31)));
    }
  }
  __syncthreads();
  const float tnb = block_reduce_sum(nbv, sb);
  if (tid == 0) atomicAdd(&scal[3], tnb);
}

extern "C" void kernel_launch(void* const* d_in, const int* in_sizes, int n_in,
                              void* d_out, int out_size, void* d_ws, size_t ws_size,
                              hipStream_t stream) {
  const float* z = (const float*)d_in[0];
  const float* nodes = (const float*)d_in[1];
  float* out = (float*)d_out;
  unsigned char* ws = (unsigned char*)d_ws;

  float* som = out + OUT_SOM;
  float* scal_out = out + OUT_SCAL;
  float* qout = out + OUT_Q;
  float* bmuf = out + OUT_BMU;

  const size_t NEED = 36839440;
  if (ws_size >= NEED) {
    ushortT* A2 = (ushortT*)(ws + 0);           // 32 MB row-major [zh|zl]
    ushortT* nhiF = (ushortT*)(ws + 33554432);  // 512 KB fragment
    ushortT* nloF = (ushortT*)(ws + 34078720);  // 512 KB fragment
    float* zn = (float*)(ws + 34603008);        // 128 KB
    float* nnorm = (float*)(ws + 34734080);     // 4 KB
    float* psum = (float*)(ws + 34738176);      // 512 x 1024 f32 = 2 MB
    float* colsum = (float*)(ws + 36835328);    // 4 KB
    float* scal = (float*)(ws + 36839424);      // 16 B

    hipMemsetAsync(scal, 0, 16, stream);

    k_conv3<<<8256, 256, 0, stream>>>(z, nodes, A2, nhiF, nloF, zn, nnorm);
    k_gemmF<<<512, 1024, 0, stream>>>(A2, nhiF, nloF, zn, nnorm, qout, bmuf, psum);
    k_cs<<<16, 256, 0, stream>>>(psum, colsum);
    k_tail<<<4352, 256, 0, stream>>>(qout, colsum, z, nodes, bmuf, nhiF, nloF, nnorm,
                                     som, scal);
    k_final<<<1, 1, 0, stream>>>(scal, scal_out);
  } else {
    float* wsf = (float*)ws;
    float* nt = wsf;
    float* nnorm = wsf + 262144;
    float* srow = wsf + 263168;
    float* colsum = wsf + 295936;
    float* scal = wsf + 296960;

    hipMemsetAsync(colsum, 0, (1024 + 4) * sizeof(float), stream);
    k_prep_fb<<<1024, 256, 0, stream>>>(nodes, nt, nnorm);
    k_div_fb<<<256, 256, 0, stream>>>(nodes, nt, nnorm, scal);
    k_dist_fb<<<512, 256, 0, stream>>>(z, nt, nnorm, qout, srow, bmuf);
    k_norm_fb<<<2048, 256, 0, stream>>>(qout, srow, colsum);
    k_kl_fb<<<2048, 256, 0, stream>>>(qout, colsum, scal);
    k_somnb_fb<<<2048, 256, 0, stream>>>(z, nodes, bmuf, som, scal);
    k_final<<<1, 1, 0, stream>>>(scal, scal_out);
  }
}